// Round 6
// baseline (129.276 us; speedup 1.0000x reference)
//
#include <hip/hip_runtime.h>

#define NUM_C 1000
#define NUM_A 512
#define PRE_BLOCKS 64
#define PRE_THREADS 1024
#define CHUNK 256
#define RED_THREADS 512

typedef float f32x4 __attribute__((ext_vector_type(4)));

// Workspace layout (bytes):
//   [0,     4096)   counts[1024] (int)
//   [4096,  8192)   cursor[1024] (int)
//   [8192, 12288)   invs[1024]   (float)  1/max(count,1)
//   [12288, 12288+4*N)  rowlist[N] (int, packed (label<<18)|row)

// --- K1: privatized histogram -------------------------------------------
__global__ __launch_bounds__(PRE_THREADS) void hist_priv_kernel(
    const int4* __restrict__ labels4, int* __restrict__ counts, int n4) {
    __shared__ int cnt[NUM_C];
    int t = threadIdx.x;
    for (int i = t; i < NUM_C; i += PRE_THREADS) cnt[i] = 0;
    __syncthreads();
    int i = blockIdx.x * PRE_THREADS + t;
    int stride = gridDim.x * PRE_THREADS;
    for (; i < n4; i += stride) {
        int4 lab = labels4[i];
        atomicAdd(&cnt[lab.x], 1);
        atomicAdd(&cnt[lab.y], 1);
        atomicAdd(&cnt[lab.z], 1);
        atomicAdd(&cnt[lab.w], 1);
    }
    __syncthreads();
    for (int j = t; j < NUM_C; j += PRE_THREADS)
        if (cnt[j] > 0) atomicAdd(&counts[j], cnt[j]);
}

// --- K2: fused scan + privatized scatter (packed entries) ---------------
__global__ __launch_bounds__(PRE_THREADS) void scan_scatter_kernel(
    const int4* __restrict__ labels4, const int* __restrict__ counts,
    int* __restrict__ cursor, float* __restrict__ invs,
    int* __restrict__ rowlist, int rows_per_blk) {
    __shared__ int buf[1024];
    __shared__ int cnt[NUM_C];
    __shared__ int base_l[NUM_C];
    int t = threadIdx.x;
    int v = (t < NUM_C) ? counts[t] : 0;
    buf[t] = v;
    for (int i = t; i < NUM_C; i += PRE_THREADS) cnt[i] = 0;
    if (blockIdx.x == 0 && t < 1024)
        invs[t] = 1.0f / (float)((t < NUM_C && v > 0) ? v : 1);
    __syncthreads();
    for (int off = 1; off < 1024; off <<= 1) {
        int x = (t >= off) ? buf[t - off] : 0;
        __syncthreads();
        buf[t] += x;
        __syncthreads();
    }
    int excl = buf[t] - v;
    buf[t] = excl;                 // buf now holds exclusive prefix
    __syncthreads();

    // thread t owns 4 consecutive rows (one int4 label load)
    int r = blockIdx.x * rows_per_blk + 4 * t;
    int4 lab = labels4[blockIdx.x * (rows_per_blk / 4) + t];
    int s0 = atomicAdd(&cnt[lab.x], 1);
    int s1 = atomicAdd(&cnt[lab.y], 1);
    int s2 = atomicAdd(&cnt[lab.z], 1);
    int s3 = atomicAdd(&cnt[lab.w], 1);
    __syncthreads();
    for (int i = t; i < NUM_C; i += PRE_THREADS) {
        int c = cnt[i];
        base_l[i] = (c > 0) ? buf[i] + atomicAdd(&cursor[i], c) : 0;
    }
    __syncthreads();
    rowlist[base_l[lab.x] + s0] = (lab.x << 18) | (r + 0);
    rowlist[base_l[lab.y] + s1] = (lab.y << 18) | (r + 1);
    rowlist[base_l[lab.z] + s2] = (lab.z << 18) | (r + 2);
    rowlist[base_l[lab.w] + s3] = (lab.w << 18) | (r + 3);
}

// --- K3: balanced chunk reduce ------------------------------------------
// Grid = N/CHUNK blocks, each handles exactly CHUNK class-sorted rows.
// 512 threads = 4 row-slots x 128 float4 quads. Running acc per thread,
// flushed on (rare, wave-uniform) class change via scaled f32 atomics into
// the zero-initialized output. mean = sum(v_i * inv_cnt) distributes.
__global__ __launch_bounds__(RED_THREADS, 8) void reduce_kernel(
    const f32x4* __restrict__ F4, const int* __restrict__ rowlist,
    const float* __restrict__ invs, float* __restrict__ out, int n) {
    int t = threadIdx.x;
    int slot = t >> 7;             // 0..3, uniform per wave-pair
    int q = t & 127;               // float4 column index

    int base = blockIdx.x * CHUNK;
    int end = base + CHUNK;
    if (end > n) end = n;

    f32x4 acc = {0.f, 0.f, 0.f, 0.f};
    int cur = -1;

    auto flush = [&]() {
        if (cur >= 0) {
            float s = invs[cur];
            float* dst = out + (size_t)cur * NUM_A + 4 * q;
            unsafeAtomicAdd(dst + 0, acc.x * s);
            unsafeAtomicAdd(dst + 1, acc.y * s);
            unsafeAtomicAdd(dst + 2, acc.z * s);
            unsafeAtomicAdd(dst + 3, acc.w * s);
        }
    };

    int k = base + slot;
    for (; k + 12 < end; k += 16) {
        int e0 = __builtin_amdgcn_readfirstlane(rowlist[k + 0]);
        int e1 = __builtin_amdgcn_readfirstlane(rowlist[k + 4]);
        int e2 = __builtin_amdgcn_readfirstlane(rowlist[k + 8]);
        int e3 = __builtin_amdgcn_readfirstlane(rowlist[k + 12]);
        f32x4 v0 = F4[(size_t)(e0 & 0x3FFFF) * (NUM_A / 4) + q];
        f32x4 v1 = F4[(size_t)(e1 & 0x3FFFF) * (NUM_A / 4) + q];
        f32x4 v2 = F4[(size_t)(e2 & 0x3FFFF) * (NUM_A / 4) + q];
        f32x4 v3 = F4[(size_t)(e3 & 0x3FFFF) * (NUM_A / 4) + q];
        int l0 = e0 >> 18, l1 = e1 >> 18, l2 = e2 >> 18, l3 = e3 >> 18;
        if (l3 == cur) {           // monotone labels: all four == cur
            acc += (v0 + v1) + (v2 + v3);
        } else {
            if (l0 != cur) { flush(); acc = {0.f,0.f,0.f,0.f}; cur = l0; }
            acc += v0;
            if (l1 != cur) { flush(); acc = {0.f,0.f,0.f,0.f}; cur = l1; }
            acc += v1;
            if (l2 != cur) { flush(); acc = {0.f,0.f,0.f,0.f}; cur = l2; }
            acc += v2;
            if (l3 != cur) { flush(); acc = {0.f,0.f,0.f,0.f}; cur = l3; }
            acc += v3;
        }
    }
    for (; k < end; k += 4) {      // safety tail (unused at N=262144)
        int e = __builtin_amdgcn_readfirstlane(rowlist[k]);
        f32x4 v = F4[(size_t)(e & 0x3FFFF) * (NUM_A / 4) + q];
        int l = e >> 18;
        if (l != cur) { flush(); acc = {0.f,0.f,0.f,0.f}; cur = l; }
        acc += v;
    }
    flush();
}

extern "C" void kernel_launch(void* const* d_in, const int* in_sizes, int n_in,
                              void* d_out, int out_size, void* d_ws, size_t ws_size,
                              hipStream_t stream) {
    const float* features = (const float*)d_in[0];
    const int* labels = (const int*)d_in[1];
    float* out = (float*)d_out;
    int n = in_sizes[1];                 // 262144
    int n4 = n / 4;
    int rows_per_blk = n / PRE_BLOCKS;   // 4096

    char* ws = (char*)d_ws;
    int* counts  = (int*)(ws + 0);
    int* cursor  = (int*)(ws + 4096);
    float* invs  = (float*)(ws + 8192);
    int* rowlist = (int*)(ws + 12288);

    hipMemsetAsync(counts, 0, 8192, stream);             // counts + cursor
    hipMemsetAsync(out, 0, (size_t)out_size * 4, stream); // atomic target

    hist_priv_kernel<<<PRE_BLOCKS, PRE_THREADS, 0, stream>>>(
        (const int4*)labels, counts, n4);
    scan_scatter_kernel<<<PRE_BLOCKS, PRE_THREADS, 0, stream>>>(
        (const int4*)labels, counts, cursor, invs, rowlist, rows_per_blk);
    int nchunks = (n + CHUNK - 1) / CHUNK;
    reduce_kernel<<<nchunks, RED_THREADS, 0, stream>>>(
        (const f32x4*)features, rowlist, invs, out, n);
}

// Round 7
// 118.537 us; speedup vs baseline: 1.0906x; 1.0906x over previous
//
#include <hip/hip_runtime.h>

#define NUM_C 1000
#define NUM_A 512
#define PRE_BLOCKS 64
#define PRE_THREADS 1024
#define RED_THREADS 512

typedef float f32x4 __attribute__((ext_vector_type(4)));

// Workspace layout (bytes):
//   [0,      4096)   starts[1024] (int)
//   [4096,   8192)   counts[1024] (int)
//   [8192,  8192+256000)  cnt_matrix[64][1000] (int)
//   [272384, ...)    rowlist[N] (int)   (1 MiB at N=262144)

// --- K1: per-block histogram, no global atomics --------------------------
__global__ __launch_bounds__(PRE_THREADS) void hist_kernel(
    const int4* __restrict__ labels4, int* __restrict__ cnt_matrix, int n4_per_blk) {
    __shared__ int cnt[NUM_C];
    int t = threadIdx.x;
    for (int i = t; i < NUM_C; i += PRE_THREADS) cnt[i] = 0;
    __syncthreads();
    int base = blockIdx.x * n4_per_blk;
    for (int j = t; j < n4_per_blk; j += PRE_THREADS) {
        int4 lab = labels4[base + j];
        atomicAdd(&cnt[lab.x], 1);
        atomicAdd(&cnt[lab.y], 1);
        atomicAdd(&cnt[lab.z], 1);
        atomicAdd(&cnt[lab.w], 1);
    }
    __syncthreads();
    int* dst = cnt_matrix + blockIdx.x * NUM_C;
    for (int i = t; i < NUM_C; i += PRE_THREADS) dst[i] = cnt[i];
}

// --- K2: scan from cnt_matrix + scatter, no global atomics ---------------
__global__ __launch_bounds__(PRE_THREADS) void scan_scatter_kernel(
    const int4* __restrict__ labels4, const int* __restrict__ cnt_matrix,
    int* __restrict__ starts, int* __restrict__ counts,
    int* __restrict__ rowlist, int rows_per_blk) {
    __shared__ int buf[1024];
    __shared__ int cnt[NUM_C];
    __shared__ int base_l[NUM_C];
    int t = threadIdx.x;
    int b = blockIdx.x;

    // column sum over blocks: total and prefix-before-me (coalesced reads)
    int total = 0, before = 0;
    if (t < NUM_C) {
        for (int bb = 0; bb < PRE_BLOCKS; ++bb) {
            int v = cnt_matrix[bb * NUM_C + t];
            total += v;
            if (bb < b) before += v;
        }
    }
    buf[t] = (t < NUM_C) ? total : 0;
    for (int i = t; i < NUM_C; i += PRE_THREADS) cnt[i] = 0;
    __syncthreads();

    // Hillis-Steele exclusive scan over class totals
    for (int off = 1; off < 1024; off <<= 1) {
        int x = (t >= off) ? buf[t - off] : 0;
        __syncthreads();
        buf[t] += x;
        __syncthreads();
    }
    int excl = buf[t] - ((t < NUM_C) ? total : 0);
    if (t < NUM_C) base_l[t] = excl + before;
    if (b == 0 && t < NUM_C) {
        starts[t] = excl;
        counts[t] = total;
    }
    __syncthreads();

    // local rank within (block, class): 4 consecutive rows per thread
    int r = b * rows_per_blk + 4 * t;
    int4 lab = labels4[b * (rows_per_blk / 4) + t];
    int s0 = atomicAdd(&cnt[lab.x], 1);
    int s1 = atomicAdd(&cnt[lab.y], 1);
    int s2 = atomicAdd(&cnt[lab.z], 1);
    int s3 = atomicAdd(&cnt[lab.w], 1);
    __syncthreads();

    rowlist[base_l[lab.x] + s0] = r + 0;
    rowlist[base_l[lab.y] + s1] = r + 1;
    rowlist[base_l[lab.z] + s2] = r + 2;
    rowlist[base_l[lab.w] + s3] = r + 3;
}

// --- K3: gather-reduce, one block per class, direct output (R5 form) -----
__global__ __launch_bounds__(RED_THREADS, 8) void reduce_kernel(
    const f32x4* __restrict__ F4,
    const int* __restrict__ starts, const int* __restrict__ counts,
    const int* __restrict__ rowlist, float* __restrict__ out) {
    int c = blockIdx.x;
    int t = threadIdx.x;
    int slot = t >> 7;             // 0..3, uniform per half-wave group
    int q = t & 127;               // float4 column index

    int start = starts[c];
    int cnt = counts[c];

    f32x4 acc = {0.f, 0.f, 0.f, 0.f};

    int k = slot;
    for (; k + 12 < cnt; k += 16) {
        int r0 = __builtin_amdgcn_readfirstlane(rowlist[start + k + 0]);
        int r1 = __builtin_amdgcn_readfirstlane(rowlist[start + k + 4]);
        int r2 = __builtin_amdgcn_readfirstlane(rowlist[start + k + 8]);
        int r3 = __builtin_amdgcn_readfirstlane(rowlist[start + k + 12]);
        f32x4 v0 = F4[(size_t)r0 * (NUM_A / 4) + q];
        f32x4 v1 = F4[(size_t)r1 * (NUM_A / 4) + q];
        f32x4 v2 = F4[(size_t)r2 * (NUM_A / 4) + q];
        f32x4 v3 = F4[(size_t)r3 * (NUM_A / 4) + q];
        acc += (v0 + v1) + (v2 + v3);
    }
    for (; k < cnt; k += 4) {
        int r = __builtin_amdgcn_readfirstlane(rowlist[start + k]);
        acc += F4[(size_t)r * (NUM_A / 4) + q];
    }

    __shared__ f32x4 sbuf[3][128];
    if (slot > 0) sbuf[slot - 1][q] = acc;
    __syncthreads();
    if (slot == 0) {
        acc += (sbuf[0][q] + sbuf[1][q]) + sbuf[2][q];
        float inv = 1.0f / (float)(cnt > 0 ? cnt : 1);
        f32x4 res = acc * inv;
        ((f32x4*)out)[(size_t)c * (NUM_A / 4) + q] = res;
    }
}

extern "C" void kernel_launch(void* const* d_in, const int* in_sizes, int n_in,
                              void* d_out, int out_size, void* d_ws, size_t ws_size,
                              hipStream_t stream) {
    const float* features = (const float*)d_in[0];
    const int* labels = (const int*)d_in[1];
    float* out = (float*)d_out;
    int n = in_sizes[1];                  // 262144
    int n4_per_blk = (n / 4) / PRE_BLOCKS;  // 1024
    int rows_per_blk = n / PRE_BLOCKS;      // 4096

    char* ws = (char*)d_ws;
    int* starts     = (int*)(ws + 0);
    int* counts     = (int*)(ws + 4096);
    int* cnt_matrix = (int*)(ws + 8192);
    int* rowlist    = (int*)(ws + 8192 + PRE_BLOCKS * NUM_C * 4);

    hist_kernel<<<PRE_BLOCKS, PRE_THREADS, 0, stream>>>(
        (const int4*)labels, cnt_matrix, n4_per_blk);
    scan_scatter_kernel<<<PRE_BLOCKS, PRE_THREADS, 0, stream>>>(
        (const int4*)labels, cnt_matrix, starts, counts, rowlist, rows_per_blk);
    reduce_kernel<<<NUM_C, RED_THREADS, 0, stream>>>(
        (const f32x4*)features, starts, counts, rowlist, out);
}